// Round 2
// baseline (666.557 us; speedup 1.0000x reference)
//
#include <hip/hip_runtime.h>

// ---------- types ----------
typedef __attribute__((ext_vector_type(8))) short short8;
typedef __attribute__((ext_vector_type(4))) float f32x4;

__device__ __forceinline__ unsigned short f2bf(float f) {
    union { float f; unsigned u; } v; v.f = f;
    unsigned r = v.u + 0x7FFFu + ((v.u >> 16) & 1u);   // RNE
    return (unsigned short)(r >> 16);
}
__device__ __forceinline__ float bf2f(unsigned short u) {
    union { unsigned u; float f; } v; v.u = ((unsigned)u) << 16;
    return v.f;
}

// ---------- K0: fp32 -> bf16 elementwise (data) ----------
__global__ __launch_bounds__(256)
void cvt_bf16_kernel(const float* __restrict__ X, unsigned short* __restrict__ Y, int n4) {
    int i = blockIdx.x * 256 + threadIdx.x;
    if (i >= n4) return;
    float4 v = ((const float4*)X)[i];
    ushort4 o; o.x = f2bf(v.x); o.y = f2bf(v.y); o.z = f2bf(v.z); o.w = f2bf(v.w);
    ((ushort4*)Y)[i] = o;
}

// ---------- K1: tiled transpose fp32 [G][K][N] -> bf16 [G][Np][K] (zero-pad n>=N) ----------
__global__ __launch_bounds__(256)
void transpose_kernel(const float* __restrict__ X, unsigned short* __restrict__ Y,
                      int K, int N, int Np) {
    __shared__ float tile[32][33];
    int g = blockIdx.z;
    const float* Xg = X + (long)g * K * N;
    unsigned short* Yg = Y + (long)g * Np * K;
    int k0 = blockIdx.x * 32, n0 = blockIdx.y * 32;
    int tx = threadIdx.x & 31, ty = threadIdx.x >> 5;   // 32 x 8
#pragma unroll
    for (int i = 0; i < 4; ++i) {
        int kk = ty + i * 8;
        int n = n0 + tx;
        tile[kk][tx] = (n < N) ? Xg[(long)(k0 + kk) * N + n] : 0.0f;
    }
    __syncthreads();
#pragma unroll
    for (int i = 0; i < 4; ++i) {
        int nn = ty + i * 8;
        Yg[(long)(n0 + nn) * K + k0 + tx] = f2bf(tile[tx][nn]);
    }
}

// ---------- K2: fuzzy membership exp(-(d-p)^2/(2 v^2)) -> bf16 chunk [NR*B, F] ----------
__global__ __launch_bounds__(128)
void fuzzy_kernel(const float* __restrict__ data, const float* __restrict__ proto,
                  const float* __restrict__ var, unsigned short* __restrict__ fuzzy,
                  int r0) {
    int rb = blockIdx.x;            // r_local*2048 + b
    int r = r0 + (rb >> 11), b = rb & 2047;
    int f = threadIdx.x * 4;
    float4 d = *(const float4*)(data + (long)b * 512 + f);
    float4 p = *(const float4*)(proto + (long)r * 512 + f);
    float4 w = *(const float4*)(var + (long)r * 512 + f);
    ushort4 o;
    float x;
    x = d.x - p.x; o.x = f2bf(__expf(-(x * x) / (2.f * w.x * w.x)));
    x = d.y - p.y; o.y = f2bf(__expf(-(x * x) / (2.f * w.y * w.y)));
    x = d.z - p.z; o.z = f2bf(__expf(-(x * x) / (2.f * w.z * w.z)));
    x = d.w - p.w; o.w = f2bf(__expf(-(x * x) / (2.f * w.w * w.w)));
    *(ushort4*)(fuzzy + (long)rb * 512 + f) = o;
}

// ---------- K3: 128x128 tile bf16 MFMA GEMM (m97 structure) ----------
// A: bf16 [M][K] row-major (+ g*sAg), Bt: bf16 [N][K] row-major (+ g*sBg),
// bias fp32 (+ g*sBiasG, cols >= biasN get 0), C: bf16 or fp32 [M][N] (+ g*sCg)
template<bool OUT_BF16, bool RELU>
__global__ __launch_bounds__(256, 2)
void gemm_kernel(const unsigned short* __restrict__ A,
                 const unsigned short* __restrict__ Bt,
                 const float* __restrict__ bias,
                 void* __restrict__ Cptr,
                 int M, int N, int K,
                 long sAg, long sBg, long sCg, int sBiasG, int biasN) {
    const int g = blockIdx.z;
    A += (long)g * sAg;
    Bt += (long)g * sBg;
    bias += (long)g * sBiasG;
    const int m0 = blockIdx.x * 128;
    const int n0 = blockIdx.y * 128;

    __shared__ __align__(16) unsigned short ldsA[128 * 32];
    __shared__ __align__(16) unsigned short ldsB[128 * 32];

    const int tid = threadIdx.x;
    const int lane = tid & 63;
    const int w = tid >> 6;            // wave 0..3
    const int wm = w >> 1, wn = w & 1; // 2x2 waves, 64x64 each
    const int r16 = lane & 15, kg = lane >> 4;

    f32x4 acc[4][4];
#pragma unroll
    for (int i = 0; i < 4; ++i)
#pragma unroll
        for (int j = 0; j < 4; ++j) {
            f32x4 z = {0.f, 0.f, 0.f, 0.f};
            acc[i][j] = z;
        }

    for (int k0 = 0; k0 < K; k0 += 32) {
#pragma unroll
        for (int j = 0; j < 2; ++j) {
            int t = j * 256 + tid;
            int row = t >> 2, kc = (t & 3) * 8;
            const unsigned short* ga = A + (long)(m0 + row) * K + k0 + kc;
            __builtin_amdgcn_global_load_lds(
                (const __attribute__((address_space(1))) void*)ga,
                (__attribute__((address_space(3))) void*)(ldsA + (j * 256 + w * 64) * 8),
                16, 0, 0);
            const unsigned short* gb = Bt + (long)(n0 + row) * K + k0 + kc;
            __builtin_amdgcn_global_load_lds(
                (const __attribute__((address_space(1))) void*)gb,
                (__attribute__((address_space(3))) void*)(ldsB + (j * 256 + w * 64) * 8),
                16, 0, 0);
        }
        __syncthreads();
        short8 aF[4], bF[4];
#pragma unroll
        for (int mt = 0; mt < 4; ++mt)
            aF[mt] = *(const short8*)(ldsA + (wm * 64 + mt * 16 + r16) * 32 + kg * 8);
#pragma unroll
        for (int nt = 0; nt < 4; ++nt)
            bF[nt] = *(const short8*)(ldsB + (wn * 64 + nt * 16 + r16) * 32 + kg * 8);
#pragma unroll
        for (int mt = 0; mt < 4; ++mt)
#pragma unroll
            for (int nt = 0; nt < 4; ++nt)
                acc[mt][nt] = __builtin_amdgcn_mfma_f32_16x16x32_bf16(
                    aF[mt], bF[nt], acc[mt][nt], 0, 0, 0);
        __syncthreads();
    }

#pragma unroll
    for (int nt = 0; nt < 4; ++nt) {
        int col = n0 + wn * 64 + nt * 16 + r16;
        float bv = (col < biasN) ? bias[col] : 0.f;
#pragma unroll
        for (int mt = 0; mt < 4; ++mt) {
#pragma unroll
            for (int j = 0; j < 4; ++j) {
                int row = m0 + wm * 64 + mt * 16 + kg * 4 + j;
                float v = acc[mt][nt][j] + bv;
                if (RELU) v = fmaxf(v, 0.f);
                if (OUT_BF16)
                    ((unsigned short*)Cptr)[(long)g * sCg + (long)row * N + col] = f2bf(v);
                else
                    ((float*)Cptr)[(long)g * sCg + (long)row * N + col] = v;
            }
        }
    }
}

// ---------- K4: GEMV  fslog[row] = h2[row,:] . w3 + b3 ----------
__global__ __launch_bounds__(256)
void gemv_fs(const unsigned short* __restrict__ h2, const float* __restrict__ w3,
             const float* __restrict__ b3, float* __restrict__ fslog) {
    int row = blockIdx.x * 4 + (threadIdx.x >> 6);
    int lane = threadIdx.x & 63;
    short8 v = *(const short8*)(h2 + (long)row * 512 + lane * 8);
    float s = 0.f;
#pragma unroll
    for (int j = 0; j < 8; ++j) s += bf2f((unsigned short)v[j]) * w3[lane * 8 + j];
#pragma unroll
    for (int off = 32; off; off >>= 1) s += __shfl_down(s, off, 64);
    if (lane == 0) fslog[row] = s + b3[0];
}

// ---------- K5: fire = softmax over rules ----------
__global__ __launch_bounds__(256)
void fire_kernel(const float* __restrict__ fslog, float* __restrict__ fire) {
    int b = blockIdx.x * 256 + threadIdx.x;   // 8 blocks x 256 = 2048
    float v[32];
    float mx = -1e30f;
#pragma unroll
    for (int r = 0; r < 32; ++r) { v[r] = fslog[r * 2048 + b]; mx = fmaxf(mx, v[r]); }
    float s = 0.f;
#pragma unroll
    for (int r = 0; r < 32; ++r) { v[r] = __expf(v[r] - mx); s += v[r]; }
    float inv = 1.f / s;
#pragma unroll
    for (int r = 0; r < 32; ++r) fire[b * 32 + r] = v[r] * inv;
}

// ---------- K6: mix[b,c] (+)= sum_{r_local} fire[b,r0+r]*logits[r,b,c] ----------
__global__ __launch_bounds__(128)
void accum_kernel(const float* __restrict__ logits, const float* __restrict__ fire,
                  float* __restrict__ mix, int r0, int NR, int first) {
    int b = blockIdx.x, c = threadIdx.x;      // 128 threads (C padded to 128)
    float acc = first ? 0.f : mix[b * 128 + c];
    for (int r = 0; r < NR; ++r)
        acc += fire[b * 32 + r0 + r] * logits[((long)r * 2048 + b) * 128 + c];
    mix[b * 128 + c] = acc;
}

// ---------- K7: out[b,c] = softmax_c(mix[b,c]) ----------
__global__ __launch_bounds__(128)
void softmax_out_kernel(const float* __restrict__ mix, float* __restrict__ out) {
    int b = blockIdx.x, c = threadIdx.x;
    __shared__ float redm[2], reds[2];
    float val = (c < 100) ? mix[b * 128 + c] : -1e30f;
    float m = val;
#pragma unroll
    for (int off = 32; off; off >>= 1) m = fmaxf(m, __shfl_xor(m, off, 64));
    int lane = c & 63, wv = c >> 6;
    if (lane == 0) redm[wv] = m;
    __syncthreads();
    m = fmaxf(redm[0], redm[1]);
    float e = (c < 100) ? __expf(val - m) : 0.f;
    float s = e;
#pragma unroll
    for (int off = 32; off; off >>= 1) s += __shfl_xor(s, off, 64);
    if (lane == 0) reds[wv] = s;
    __syncthreads();
    s = reds[0] + reds[1];
    if (c < 100) out[b * 100 + c] = e / s;
}

// ---------- launch ----------
extern "C" void kernel_launch(void* const* d_in, const int* in_sizes, int n_in,
                              void* d_out, int out_size, void* d_ws, size_t ws_size,
                              hipStream_t stream) {
    const float* data  = (const float*)d_in[0];
    const float* proto = (const float*)d_in[1];
    const float* var   = (const float*)d_in[2];
    const float* fs_w1 = (const float*)d_in[3];
    const float* fs_b1 = (const float*)d_in[4];
    const float* fs_w2 = (const float*)d_in[5];
    const float* fs_b2 = (const float*)d_in[6];
    const float* fs_w3 = (const float*)d_in[7];
    const float* fs_b3 = (const float*)d_in[8];
    const float* cq_w1 = (const float*)d_in[9];
    const float* cq_b1 = (const float*)d_in[10];
    const float* cq_w2 = (const float*)d_in[11];
    const float* cq_b2 = (const float*)d_in[12];
    const float* cq_w3 = (const float*)d_in[13];
    const float* cq_b3 = (const float*)d_in[14];
    float* out = (float*)d_out;

    // ---- adaptive workspace layout: chunk over NR rules ----
    const size_t PERSIST =
        2097152 /*data_bf*/ + 1048576 /*w1t*/ + 1048576 /*w2t*/ +
        262144 /*fslog*/ + 262144 /*fire*/ + 1048576 /*mix*/;
    const size_t CHUNK_UNIT =
        2097152 /*cF*/ + 4194304 /*cH1*/ + 2097152 /*cH2*/ +
        1048576 /*cW1t*/ + 1048576 /*cW2t*/ + 131072 /*cW3t*/;  // per rule
    int NR = 8;
    while (NR > 1 && PERSIST + (size_t)NR * CHUNK_UNIT > ws_size) NR >>= 1;
    const int nch = 32 / NR;

    char* ws = (char*)d_ws;
    size_t off = 0;
    auto take = [&](size_t bytes) { char* p = ws + off; off += bytes; return p; };
    unsigned short* data_bf = (unsigned short*)take(2097152);
    unsigned short* w1t     = (unsigned short*)take(1048576);
    unsigned short* w2t     = (unsigned short*)take(1048576);
    float*          fslog   = (float*)take(262144);
    float*          fire    = (float*)take(262144);
    float*          mix     = (float*)take(1048576);
    unsigned short* cF      = (unsigned short*)take((size_t)NR * 2097152);  // fuzzy / g2
    unsigned short* cH1     = (unsigned short*)take((size_t)NR * 4194304);  // h1 / g1
    unsigned short* cH2     = (unsigned short*)take((size_t)NR * 2097152);  // h2 / logits(fp32)
    unsigned short* cW1t    = (unsigned short*)take((size_t)NR * 1048576);
    unsigned short* cW2t    = (unsigned short*)take((size_t)NR * 1048576);
    unsigned short* cW3t    = (unsigned short*)take((size_t)NR * 131072);

    // persistent conversions
    cvt_bf16_kernel<<<1024, 256, 0, stream>>>(data, data_bf, 262144);
    transpose_kernel<<<dim3(16, 32, 1), 256, 0, stream>>>(fs_w1, w1t, 512, 1024, 1024);
    transpose_kernel<<<dim3(32, 16, 1), 256, 0, stream>>>(fs_w2, w2t, 1024, 512, 512);

    // ---- pass 1: fire-strength chain, chunked ----
    for (int ch = 0; ch < nch; ++ch) {
        const int r0 = ch * NR;
        fuzzy_kernel<<<NR * 2048, 128, 0, stream>>>(data, proto, var, cF, r0);
        gemm_kernel<true, true><<<dim3(NR * 16, 8, 1), 256, 0, stream>>>(
            cF, w1t, fs_b1, cH1, NR * 2048, 1024, 512, 0, 0, 0, 0, 1024);
        gemm_kernel<true, true><<<dim3(NR * 16, 4, 1), 256, 0, stream>>>(
            cH1, w2t, fs_b2, cH2, NR * 2048, 512, 1024, 0, 0, 0, 0, 512);
        gemv_fs<<<NR * 512, 256, 0, stream>>>(cH2, fs_w3, fs_b3, fslog + (long)r0 * 2048);
    }
    fire_kernel<<<8, 256, 0, stream>>>(fslog, fire);

    // ---- pass 2: consequent chain, chunked, accumulate mixture ----
    for (int ch = 0; ch < nch; ++ch) {
        const int r0 = ch * NR;
        transpose_kernel<<<dim3(16, 32, NR), 256, 0, stream>>>(
            cq_w1 + (long)r0 * 512 * 1024, cW1t, 512, 1024, 1024);
        transpose_kernel<<<dim3(32, 16, NR), 256, 0, stream>>>(
            cq_w2 + (long)r0 * 1024 * 512, cW2t, 1024, 512, 512);
        transpose_kernel<<<dim3(16, 4, NR), 256, 0, stream>>>(
            cq_w3 + (long)r0 * 512 * 100, cW3t, 512, 100, 128);
        gemm_kernel<true, true><<<dim3(16, 8, NR), 256, 0, stream>>>(
            data_bf, cW1t, cq_b1 + (long)r0 * 1024, cH1, 2048, 1024, 512,
            0, (long)1024 * 512, (long)2048 * 1024, 1024, 1024);
        gemm_kernel<true, true><<<dim3(16, 4, NR), 256, 0, stream>>>(
            cH1, cW2t, cq_b2 + (long)r0 * 512, cF, 2048, 512, 1024,
            (long)2048 * 1024, (long)512 * 1024, (long)2048 * 512, 512, 512);
        gemm_kernel<false, false><<<dim3(16, 1, NR), 256, 0, stream>>>(
            cF, cW3t, cq_b3 + (long)r0 * 100, (float*)cH2, 2048, 128, 512,
            (long)2048 * 512, (long)128 * 512, (long)2048 * 128, 100, 100);
        accum_kernel<<<2048, 128, 0, stream>>>(
            (const float*)cH2, fire, mix, r0, NR, ch == 0);
    }
    softmax_out_kernel<<<2048, 128, 0, stream>>>(mix, out);
}

// Round 3
// 549.845 us; speedup vs baseline: 1.2123x; 1.2123x over previous
//
#include <hip/hip_runtime.h>

// ---------- types ----------
typedef __attribute__((ext_vector_type(8))) short short8;
typedef __attribute__((ext_vector_type(4))) float f32x4;

__device__ __forceinline__ unsigned short f2bf(float f) {
    union { float f; unsigned u; } v; v.f = f;
    unsigned r = v.u + 0x7FFFu + ((v.u >> 16) & 1u);   // RNE
    return (unsigned short)(r >> 16);
}
__device__ __forceinline__ float bf2f(unsigned short u) {
    union { unsigned u; float f; } v; v.u = ((unsigned)u) << 16;
    return v.f;
}

// ---------- K0: fp32 -> bf16 elementwise (data) ----------
__global__ __launch_bounds__(256)
void cvt_bf16_kernel(const float* __restrict__ X, unsigned short* __restrict__ Y, int n4) {
    int i = blockIdx.x * 256 + threadIdx.x;
    if (i >= n4) return;
    float4 v = ((const float4*)X)[i];
    ushort4 o; o.x = f2bf(v.x); o.y = f2bf(v.y); o.z = f2bf(v.z); o.w = f2bf(v.w);
    ((ushort4*)Y)[i] = o;
}

// ---------- K1: tiled transpose fp32 [G][K][N] -> bf16 [G][Np][K] (zero-pad n>=N) ----------
__global__ __launch_bounds__(256)
void transpose_kernel(const float* __restrict__ X, unsigned short* __restrict__ Y,
                      int K, int N, int Np) {
    __shared__ float tile[32][33];
    int g = blockIdx.z;
    const float* Xg = X + (long)g * K * N;
    unsigned short* Yg = Y + (long)g * Np * K;
    int k0 = blockIdx.x * 32, n0 = blockIdx.y * 32;
    int tx = threadIdx.x & 31, ty = threadIdx.x >> 5;   // 32 x 8
#pragma unroll
    for (int i = 0; i < 4; ++i) {
        int kk = ty + i * 8;
        int n = n0 + tx;
        tile[kk][tx] = (n < N) ? Xg[(long)(k0 + kk) * N + n] : 0.0f;
    }
    __syncthreads();
#pragma unroll
    for (int i = 0; i < 4; ++i) {
        int nn = ty + i * 8;
        Yg[(long)(n0 + nn) * K + k0 + tx] = f2bf(tile[tx][nn]);
    }
}

// ---------- K2: fuzzy membership exp(-(d-p)^2/(2 v^2)) -> bf16 chunk [p1r*B, F] ----------
__global__ __launch_bounds__(128)
void fuzzy_kernel(const float* __restrict__ data, const float* __restrict__ proto,
                  const float* __restrict__ var, unsigned short* __restrict__ fuzzy,
                  int r0) {
    int rb = blockIdx.x;            // r_local*2048 + b
    int r = r0 + (rb >> 11), b = rb & 2047;
    int f = threadIdx.x * 4;
    float4 d = *(const float4*)(data + (long)b * 512 + f);
    float4 p = *(const float4*)(proto + (long)r * 512 + f);
    float4 w = *(const float4*)(var + (long)r * 512 + f);
    ushort4 o;
    float x;
    x = d.x - p.x; o.x = f2bf(__expf(-(x * x) / (2.f * w.x * w.x)));
    x = d.y - p.y; o.y = f2bf(__expf(-(x * x) / (2.f * w.y * w.y)));
    x = d.z - p.z; o.z = f2bf(__expf(-(x * x) / (2.f * w.z * w.z)));
    x = d.w - p.w; o.w = f2bf(__expf(-(x * x) / (2.f * w.w * w.w)));
    *(ushort4*)(fuzzy + (long)rb * 512 + f) = o;
}

// ---------- K3: 128x128 tile bf16 MFMA GEMM (m97 structure), 1-D grid + XCD swizzle ----------
// EPI: 0 = store bf16 C, 1 = fused row-dot with w3 -> atomicAdd fslog (no C store), 2 = store f32 C
// A: bf16 [M][K] (+ g*sAg), Bt: bf16 [N][K] (+ g*sBg), bias fp32 (+ g*sBiasG; cols >= biasN get 0)
template<int EPI, bool RELU>
__global__ __launch_bounds__(256, 2)
void gemm_kernel(const unsigned short* __restrict__ A,
                 const unsigned short* __restrict__ Bt,
                 const float* __restrict__ bias,
                 void* __restrict__ Cptr,
                 const float* __restrict__ w3,
                 float* __restrict__ fslog,
                 int nM, int nN, int K,
                 long sAg, long sBg, long sCg, int sBiasG, int biasN) {
    // --- bijective XCD-chunk swizzle over the flat grid (tot % 8 == 0 guaranteed by launcher) ---
    unsigned tot = gridDim.x;
    unsigned bid = blockIdx.x;
    unsigned sw = (tot & 7u) == 0 ? (bid & 7u) * (tot >> 3) + (bid >> 3) : bid;
    unsigned pg = (unsigned)nM * (unsigned)nN;
    unsigned g = sw / pg;
    unsigned rem = sw - g * pg;
    unsigned mt_ = rem / (unsigned)nN;       // n fastest: consecutive ids share the A panel
    unsigned nt_ = rem - mt_ * (unsigned)nN;
    const int N = nN * 128;
    A += (long)g * sAg;
    Bt += (long)g * sBg;
    bias += (long)g * sBiasG;
    const int m0 = (int)mt_ * 128;
    const int n0 = (int)nt_ * 128;

    __shared__ __align__(16) unsigned short ldsA[128 * 32];
    __shared__ __align__(16) unsigned short ldsB[128 * 32];

    const int tid = threadIdx.x;
    const int lane = tid & 63;
    const int w = tid >> 6;            // wave 0..3
    const int wm = w >> 1, wn = w & 1; // 2x2 waves, 64x64 each
    const int r16 = lane & 15, kg = lane >> 4;

    f32x4 acc[4][4];
#pragma unroll
    for (int i = 0; i < 4; ++i)
#pragma unroll
        for (int j = 0; j < 4; ++j) {
            f32x4 z = {0.f, 0.f, 0.f, 0.f};
            acc[i][j] = z;
        }

    for (int k0 = 0; k0 < K; k0 += 32) {
#pragma unroll
        for (int j = 0; j < 2; ++j) {
            int t = j * 256 + tid;
            int row = t >> 2, kc = (t & 3) * 8;
            const unsigned short* ga = A + (long)(m0 + row) * K + k0 + kc;
            __builtin_amdgcn_global_load_lds(
                (const __attribute__((address_space(1))) void*)ga,
                (__attribute__((address_space(3))) void*)(ldsA + (j * 256 + w * 64) * 8),
                16, 0, 0);
            const unsigned short* gb = Bt + (long)(n0 + row) * K + k0 + kc;
            __builtin_amdgcn_global_load_lds(
                (const __attribute__((address_space(1))) void*)gb,
                (__attribute__((address_space(3))) void*)(ldsB + (j * 256 + w * 64) * 8),
                16, 0, 0);
        }
        __syncthreads();
        short8 aF[4], bF[4];
#pragma unroll
        for (int mt = 0; mt < 4; ++mt)
            aF[mt] = *(const short8*)(ldsA + (wm * 64 + mt * 16 + r16) * 32 + kg * 8);
#pragma unroll
        for (int nt = 0; nt < 4; ++nt)
            bF[nt] = *(const short8*)(ldsB + (wn * 64 + nt * 16 + r16) * 32 + kg * 8);
#pragma unroll
        for (int mt = 0; mt < 4; ++mt)
#pragma unroll
            for (int nt = 0; nt < 4; ++nt)
                acc[mt][nt] = __builtin_amdgcn_mfma_f32_16x16x32_bf16(
                    aF[mt], bF[nt], acc[mt][nt], 0, 0, 0);
        __syncthreads();
    }

    // ---------- epilogue ----------
    if constexpr (EPI == 1) {
        // fused GEMV: fslog[row] += sum_col relu(C[row,col]+bias[col]) * w3[col]
        float w3v[4], bv[4];
#pragma unroll
        for (int nt = 0; nt < 4; ++nt) {
            int col = n0 + wn * 64 + nt * 16 + r16;
            w3v[nt] = w3[col];
            bv[nt] = bias[col];
        }
#pragma unroll
        for (int mt = 0; mt < 4; ++mt) {
#pragma unroll
            for (int j = 0; j < 4; ++j) {
                float p = 0.f;
#pragma unroll
                for (int nt = 0; nt < 4; ++nt) {
                    float v = acc[mt][nt][j] + bv[nt];
                    if (RELU) v = fmaxf(v, 0.f);
                    p += v * w3v[nt];
                }
                p += __shfl_xor(p, 1, 64);
                p += __shfl_xor(p, 2, 64);
                p += __shfl_xor(p, 4, 64);
                p += __shfl_xor(p, 8, 64);
                if (r16 == 0) {
                    int row = m0 + wm * 64 + mt * 16 + kg * 4 + j;
                    atomicAdd(&fslog[row], p);
                }
            }
        }
    } else {
#pragma unroll
        for (int nt = 0; nt < 4; ++nt) {
            int col = n0 + wn * 64 + nt * 16 + r16;
            float bv = (col < biasN) ? bias[col] : 0.f;
#pragma unroll
            for (int mt = 0; mt < 4; ++mt) {
#pragma unroll
                for (int j = 0; j < 4; ++j) {
                    int row = m0 + wm * 64 + mt * 16 + kg * 4 + j;
                    float v = acc[mt][nt][j] + bv;
                    if (RELU) v = fmaxf(v, 0.f);
                    if constexpr (EPI == 0)
                        ((unsigned short*)Cptr)[(long)g * sCg + (long)row * N + col] = f2bf(v);
                    else
                        ((float*)Cptr)[(long)g * sCg + (long)row * N + col] = v;
                }
            }
        }
    }
}

// ---------- K5: fire = softmax over rules (fs_b3 constant shift dropped: softmax-invariant) ----------
__global__ __launch_bounds__(256)
void fire_kernel(const float* __restrict__ fslog, float* __restrict__ fire) {
    int b = blockIdx.x * 256 + threadIdx.x;   // 8 blocks x 256 = 2048
    float v[32];
    float mx = -1e30f;
#pragma unroll
    for (int r = 0; r < 32; ++r) { v[r] = fslog[r * 2048 + b]; mx = fmaxf(mx, v[r]); }
    float s = 0.f;
#pragma unroll
    for (int r = 0; r < 32; ++r) { v[r] = __expf(v[r] - mx); s += v[r]; }
    float inv = 1.f / s;
#pragma unroll
    for (int r = 0; r < 32; ++r) fire[b * 32 + r] = v[r] * inv;
}

// ---------- K6: mix[b,c] (+)= sum_{r_local} fire[b,r0+r]*logits[r,b,c] ----------
__global__ __launch_bounds__(128)
void accum_kernel(const float* __restrict__ logits, const float* __restrict__ fire,
                  float* __restrict__ mix, int r0, int NR, int first) {
    int b = blockIdx.x, c = threadIdx.x;      // 128 threads (C padded to 128)
    float acc = first ? 0.f : mix[b * 128 + c];
    for (int r = 0; r < NR; ++r)
        acc += fire[b * 32 + r0 + r] * logits[((long)r * 2048 + b) * 128 + c];
    mix[b * 128 + c] = acc;
}

// ---------- K7: out[b,c] = softmax_c(mix[b,c]) ----------
__global__ __launch_bounds__(128)
void softmax_out_kernel(const float* __restrict__ mix, float* __restrict__ out) {
    int b = blockIdx.x, c = threadIdx.x;
    __shared__ float redm[2], reds[2];
    float val = (c < 100) ? mix[b * 128 + c] : -1e30f;
    float m = val;
#pragma unroll
    for (int off = 32; off; off >>= 1) m = fmaxf(m, __shfl_xor(m, off, 64));
    int lane = c & 63, wv = c >> 6;
    if (lane == 0) redm[wv] = m;
    __syncthreads();
    m = fmaxf(redm[0], redm[1]);
    float e = (c < 100) ? __expf(val - m) : 0.f;
    float s = e;
#pragma unroll
    for (int off = 32; off; off >>= 1) s += __shfl_xor(s, off, 64);
    if (lane == 0) reds[wv] = s;
    __syncthreads();
    s = reds[0] + reds[1];
    if (c < 100) out[b * 100 + c] = e / s;
}

// ---------- launch ----------
extern "C" void kernel_launch(void* const* d_in, const int* in_sizes, int n_in,
                              void* d_out, int out_size, void* d_ws, size_t ws_size,
                              hipStream_t stream) {
    const float* data  = (const float*)d_in[0];
    const float* proto = (const float*)d_in[1];
    const float* var   = (const float*)d_in[2];
    const float* fs_w1 = (const float*)d_in[3];
    const float* fs_b1 = (const float*)d_in[4];
    const float* fs_w2 = (const float*)d_in[5];
    const float* fs_b2 = (const float*)d_in[6];
    const float* fs_w3 = (const float*)d_in[7];
    const float* cq_w1 = (const float*)d_in[9];
    const float* cq_b1 = (const float*)d_in[10];
    const float* cq_w2 = (const float*)d_in[11];
    const float* cq_b2 = (const float*)d_in[12];
    const float* cq_w3 = (const float*)d_in[13];
    const float* cq_b3 = (const float*)d_in[14];
    float* out = (float*)d_out;

    // ---- adaptive config: pass-1 rules/chunk (p1r), pass-2 rules/chunk (p2r) ----
    const size_t PERSIST = 2097152 + 1048576 + 1048576 + 262144 + 262144 + 1048576; // 5,767,168
    const size_t PER_RULE_P2 = 1048576 + 1048576 + 131072 + 2097152;                // cW1t+cW2t+cW3t+g2
    auto need = [&](int p1r, int p2r) -> size_t {
        size_t logitsC = (size_t)p2r * 2048 * 128 * 4;
        size_t R0 = (size_t)p1r * 2048 * 512 * 2;            // fuzzy chunk
        size_t r0p2 = (size_t)p2r * PER_RULE_P2;
        if (r0p2 > R0) R0 = r0p2;
        size_t R1 = (size_t)p1r * 2048 * 1024 * 2;           // h1 chunk (>= g1 chunk)
        size_t g1b = (size_t)p2r * 2048 * 1024 * 2;
        if (g1b > R1) R1 = g1b;
        return PERSIST + logitsC + R0 + R1;
    };
    int p1r = 32, p2r = 16;
    while (need(p1r, p2r) > ws_size && p1r > 2) { p1r >>= 1; p2r >>= 1; }

    char* ws = (char*)d_ws;
    size_t off = 0;
    auto take = [&](size_t bytes) { char* p = ws + off; off += bytes; return p; };
    unsigned short* data_bf = (unsigned short*)take(2097152);
    unsigned short* w1t     = (unsigned short*)take(1048576);
    unsigned short* w2t     = (unsigned short*)take(1048576);
    float*          fslog   = (float*)take(262144);
    float*          fire    = (float*)take(262144);
    float*          mix     = (float*)take(1048576);
    float*          logitsC = (float*)take((size_t)p2r * 2048 * 128 * 4);
    size_t R0sz = (size_t)p1r * 2048 * 512 * 2;
    { size_t t = (size_t)p2r * PER_RULE_P2; if (t > R0sz) R0sz = t; }
    char* R0 = take(R0sz);
    size_t R1sz = (size_t)p1r * 2048 * 1024 * 2;
    char* R1 = take(R1sz);

    unsigned short* cF   = (unsigned short*)R0;                           // pass-1 fuzzy chunk
    unsigned short* cW1t = (unsigned short*)R0;                           // pass-2 aliases
    unsigned short* cW2t = (unsigned short*)(R0 + (size_t)p2r * 1048576);
    unsigned short* cW3t = (unsigned short*)(R0 + (size_t)p2r * 2097152);
    unsigned short* g2   = (unsigned short*)(R0 + (size_t)p2r * 2097152 + (size_t)p2r * 131072);
    unsigned short* h1   = (unsigned short*)R1;                           // pass-1 h1 / pass-2 g1
    unsigned short* g1   = (unsigned short*)R1;

    // ---- prologue ----
    cvt_bf16_kernel<<<1024, 256, 0, stream>>>(data, data_bf, 262144);
    transpose_kernel<<<dim3(16, 32, 1), 256, 0, stream>>>(fs_w1, w1t, 512, 1024, 1024);
    transpose_kernel<<<dim3(32, 16, 1), 256, 0, stream>>>(fs_w2, w2t, 1024, 512, 512);
    hipMemsetAsync(fslog, 0, 262144, stream);

    // ---- pass 1: fire-strength chain (fused GEMV via atomics) ----
    for (int ch = 0; ch < 32 / p1r; ++ch) {
        const int r0 = ch * p1r;
        fuzzy_kernel<<<p1r * 2048, 128, 0, stream>>>(data, proto, var, cF, r0);
        gemm_kernel<0, true><<<p1r * 16 * 8, 256, 0, stream>>>(
            cF, w1t, fs_b1, h1, nullptr, nullptr,
            p1r * 16, 8, 512, 0, 0, 0, 0, 1024);
        gemm_kernel<1, true><<<p1r * 16 * 4, 256, 0, stream>>>(
            h1, w2t, fs_b2, nullptr, fs_w3, fslog + (long)r0 * 2048,
            p1r * 16, 4, 1024, 0, 0, 0, 0, 512);
    }
    fire_kernel<<<8, 256, 0, stream>>>(fslog, fire);

    // ---- pass 2: consequent chain, chunked, accumulate mixture ----
    for (int ch = 0; ch < 32 / p2r; ++ch) {
        const int r0 = ch * p2r;
        transpose_kernel<<<dim3(16, 32, p2r), 256, 0, stream>>>(
            cq_w1 + (long)r0 * 512 * 1024, cW1t, 512, 1024, 1024);
        transpose_kernel<<<dim3(32, 16, p2r), 256, 0, stream>>>(
            cq_w2 + (long)r0 * 1024 * 512, cW2t, 1024, 512, 512);
        transpose_kernel<<<dim3(16, 4, p2r), 256, 0, stream>>>(
            cq_w3 + (long)r0 * 512 * 100, cW3t, 512, 100, 128);
        gemm_kernel<0, true><<<16 * 8 * p2r, 256, 0, stream>>>(
            data_bf, cW1t, cq_b1 + (long)r0 * 1024, g1, nullptr, nullptr,
            16, 8, 512, 0, (long)1024 * 512, (long)2048 * 1024, 1024, 1024);
        gemm_kernel<0, true><<<16 * 4 * p2r, 256, 0, stream>>>(
            g1, cW2t, cq_b2 + (long)r0 * 512, g2, nullptr, nullptr,
            16, 4, 1024, (long)2048 * 1024, (long)512 * 1024, (long)2048 * 512, 512, 512);
        gemm_kernel<2, false><<<16 * 1 * p2r, 256, 0, stream>>>(
            g2, cW3t, cq_b3 + (long)r0 * 100, logitsC, nullptr, nullptr,
            16, 1, 512, (long)2048 * 512, (long)128 * 512, (long)2048 * 128, 100, 100);
        accum_kernel<<<2048, 128, 0, stream>>>(logitsC, fire, mix, r0, p2r, ch == 0);
    }
    softmax_out_kernel<<<2048, 128, 0, stream>>>(mix, out);
}

// Round 4
// 536.737 us; speedup vs baseline: 1.2419x; 1.0244x over previous
//
#include <hip/hip_runtime.h>

// ---------- types ----------
typedef __attribute__((ext_vector_type(8))) short short8;
typedef __attribute__((ext_vector_type(4))) float f32x4;

__device__ __forceinline__ unsigned short f2bf(float f) {
    union { float f; unsigned u; } v; v.f = f;
    unsigned r = v.u + 0x7FFFu + ((v.u >> 16) & 1u);   // RNE
    return (unsigned short)(r >> 16);
}
__device__ __forceinline__ float bf2f(unsigned short u) {
    union { unsigned u; float f; } v; v.u = ((unsigned)u) << 16;
    return v.f;
}

// ---------- K0: fp32 -> bf16 elementwise ----------
__global__ __launch_bounds__(256)
void cvt_bf16_kernel(const float* __restrict__ X, unsigned short* __restrict__ Y, int n4) {
    int i = blockIdx.x * 256 + threadIdx.x;
    if (i >= n4) return;
    float4 v = ((const float4*)X)[i];
    ushort4 o; o.x = f2bf(v.x); o.y = f2bf(v.y); o.z = f2bf(v.z); o.w = f2bf(v.w);
    ((ushort4*)Y)[i] = o;
}

// ---------- K1: tiled transpose fp32 [G][K][N] -> bf16 [G][Np][K] ----------
__global__ __launch_bounds__(256)
void transpose_kernel(const float* __restrict__ X, unsigned short* __restrict__ Y,
                      int K, int N, int Np) {
    __shared__ float tile[32][33];
    int g = blockIdx.z;
    const float* Xg = X + (long)g * K * N;
    unsigned short* Yg = Y + (long)g * Np * K;
    int k0 = blockIdx.x * 32, n0 = blockIdx.y * 32;
    int tx = threadIdx.x & 31, ty = threadIdx.x >> 5;
#pragma unroll
    for (int i = 0; i < 4; ++i) {
        int kk = ty + i * 8;
        int n = n0 + tx;
        tile[kk][tx] = (n < N) ? Xg[(long)(k0 + kk) * N + n] : 0.0f;
    }
    __syncthreads();
#pragma unroll
    for (int i = 0; i < 4; ++i) {
        int nn = ty + i * 8;
        Yg[(long)(n0 + nn) * K + k0 + tx] = f2bf(tile[tx][nn]);
    }
}

// ---------- K2: fuzzy membership -> bf16 [p1r*B, F] ----------
__global__ __launch_bounds__(128)
void fuzzy_kernel(const float* __restrict__ data, const float* __restrict__ proto,
                  const float* __restrict__ var, unsigned short* __restrict__ fuzzy,
                  int r0) {
    int rb = blockIdx.x;
    int r = r0 + (rb >> 11), b = rb & 2047;
    int f = threadIdx.x * 4;
    float4 d = *(const float4*)(data + (long)b * 512 + f);
    float4 p = *(const float4*)(proto + (long)r * 512 + f);
    float4 w = *(const float4*)(var + (long)r * 512 + f);
    ushort4 o;
    float x;
    x = d.x - p.x; o.x = f2bf(__expf(-(x * x) / (2.f * w.x * w.x)));
    x = d.y - p.y; o.y = f2bf(__expf(-(x * x) / (2.f * w.y * w.y)));
    x = d.z - p.z; o.z = f2bf(__expf(-(x * x) / (2.f * w.z * w.z)));
    x = d.w - p.w; o.w = f2bf(__expf(-(x * x) / (2.f * w.w * w.w)));
    *(ushort4*)(fuzzy + (long)rb * 512 + f) = o;
}

// ---------- K3: 256x256 ring-4 deep-pipelined bf16 MFMA GEMM ----------
// Counted vmcnt across raw barriers (T3/T4), LDS k-chunk XOR swizzle (T2, both-sides),
// setprio around MFMA (T5), XCD-chunk swizzle (T1).
// A: bf16 [M][K] (+g*sAg), Bt: bf16 [N][K] (+g*sBg), bias fp32 [N] (+g*sBiasG).
// EPI: 0 = store bf16 C (+relu), 1 = fused dot with w3 -> atomicAdd fslog.
#define RING_WAIT_BARRIER(n)                                        \
    asm volatile("s_waitcnt vmcnt(" #n ")" ::: "memory");           \
    __builtin_amdgcn_sched_barrier(0);                              \
    __builtin_amdgcn_s_barrier();                                   \
    __builtin_amdgcn_sched_barrier(0);

template<int EPI, bool RELU>
__global__ __launch_bounds__(512, 2)
void gemm256_kernel(const unsigned short* __restrict__ A,
                    const unsigned short* __restrict__ Bt,
                    const float* __restrict__ bias,
                    void* __restrict__ Cptr,
                    const float* __restrict__ w3,
                    float* __restrict__ fslog,
                    int nM, int nN, int K,
                    long sAg, long sBg, long sCg, int sBiasG) {
    // bijective XCD-chunk swizzle (launcher guarantees gridDim.x % 8 == 0)
    unsigned tot = gridDim.x, bid = blockIdx.x;
    unsigned sw = (bid & 7u) * (tot >> 3) + (bid >> 3);
    unsigned pg = (unsigned)(nM * nN);
    unsigned g = sw / pg;
    unsigned rem = sw - g * pg;
    const int m0 = (int)(rem / (unsigned)nN) * 256;
    const int n0 = (int)(rem % (unsigned)nN) * 256;
    const int N = nN * 256;
    A += (long)g * sAg; Bt += (long)g * sBg; bias += (long)g * sBiasG;

    // 8 slots of 256 rows x 32 k bf16 (16KB): [0..3]=A ring, [4..7]=B ring. 128KB total.
    __shared__ __align__(16) unsigned short lds[8][8192];

    const int tid = threadIdx.x;
    const int lane = tid & 63;
    const int w = tid >> 6;           // 8 waves
    const int wm = w >> 2, wn = w & 3;
    const int r16 = lane & 15, kg = lane >> 4;

    f32x4 acc[8][4];
#pragma unroll
    for (int i = 0; i < 8; ++i)
#pragma unroll
        for (int j = 0; j < 4; ++j) {
            f32x4 z = {0.f, 0.f, 0.f, 0.f};
            acc[i][j] = z;
        }

    const int nsteps = K >> 5;

    // stage K-tile kt into ring slot: linear LDS dest, inverse-swizzled global source
    auto STAGE = [&](int slot, int kt) {
        const int k0 = kt << 5;
#pragma unroll
        for (int j = 0; j < 2; ++j) {
            int f = j * 512 + tid;
            int row = f >> 2, sl = f & 3;
            int kk = (sl ^ ((row >> 1) & 3)) << 3;     // T2 inverse swizzle on source
            const unsigned short* ga = A + (long)(m0 + row) * K + k0 + kk;
            __builtin_amdgcn_global_load_lds(
                (const __attribute__((address_space(1))) void*)ga,
                (__attribute__((address_space(3))) void*)(&lds[slot][0] + (j * 512 + w * 64) * 8),
                16, 0, 0);
            const unsigned short* gb = Bt + (long)(n0 + row) * K + k0 + kk;
            __builtin_amdgcn_global_load_lds(
                (const __attribute__((address_space(1))) void*)gb,
                (__attribute__((address_space(3))) void*)(&lds[4 + slot][0] + (j * 512 + w * 64) * 8),
                16, 0, 0);
        }
    };

    auto COMPUTE = [&](int slot) {
        short8 aF[8], bF[4];
#pragma unroll
        for (int mt = 0; mt < 8; ++mt) {
            int R = wm * 128 + mt * 16 + r16;
            aF[mt] = *(const short8*)(&lds[slot][0] + R * 32 + ((kg ^ ((R >> 1) & 3)) << 3));
        }
#pragma unroll
        for (int nt = 0; nt < 4; ++nt) {
            int R = wn * 64 + nt * 16 + r16;
            bF[nt] = *(const short8*)(&lds[4 + slot][0] + R * 32 + ((kg ^ ((R >> 1) & 3)) << 3));
        }
        __builtin_amdgcn_s_setprio(1);
#pragma unroll
        for (int mt = 0; mt < 8; ++mt)
#pragma unroll
            for (int nt = 0; nt < 4; ++nt)
                acc[mt][nt] = __builtin_amdgcn_mfma_f32_16x16x32_bf16(
                    aF[mt], bF[nt], acc[mt][nt], 0, 0, 0);
        __builtin_amdgcn_s_setprio(0);
        asm volatile("" ::: "memory");
        __builtin_amdgcn_s_barrier();          // all waves' ds_reads of this slot done
        __builtin_amdgcn_sched_barrier(0);
    };

    // prologue: 3 tiles in flight
    STAGE(0, 0); STAGE(1, 1); STAGE(2, 2);
    // main loop: counted vmcnt(8) -> tiles <= t+1 resident at the barrier
    for (int t = 0; t <= nsteps - 3; ++t) {
        if (t + 3 < nsteps) STAGE((t + 3) & 3, t + 3);
        RING_WAIT_BARRIER(8);
        COMPUTE(t & 3);
    }
    { RING_WAIT_BARRIER(4); COMPUTE((nsteps - 2) & 3); }
    { RING_WAIT_BARRIER(0); COMPUTE((nsteps - 1) & 3); }

    // ---------- epilogue ----------
    if constexpr (EPI == 1) {
        float w3v[4], bv[4];
#pragma unroll
        for (int nt = 0; nt < 4; ++nt) {
            int col = n0 + wn * 64 + nt * 16 + r16;
            w3v[nt] = w3[col];
            bv[nt] = bias[col];
        }
#pragma unroll
        for (int mt = 0; mt < 8; ++mt) {
#pragma unroll
            for (int j = 0; j < 4; ++j) {
                float p = 0.f;
#pragma unroll
                for (int nt = 0; nt < 4; ++nt) {
                    float v = acc[mt][nt][j] + bv[nt];
                    if (RELU) v = fmaxf(v, 0.f);
                    p += v * w3v[nt];
                }
                p += __shfl_xor(p, 1, 64);
                p += __shfl_xor(p, 2, 64);
                p += __shfl_xor(p, 4, 64);
                p += __shfl_xor(p, 8, 64);
                if (r16 == 0) {
                    int row = m0 + wm * 128 + mt * 16 + kg * 4 + j;
                    atomicAdd(&fslog[row], p);
                }
            }
        }
    } else {
#pragma unroll
        for (int nt = 0; nt < 4; ++nt) {
            int col = n0 + wn * 64 + nt * 16 + r16;
            float bv = bias[col];
#pragma unroll
            for (int mt = 0; mt < 8; ++mt) {
#pragma unroll
                for (int j = 0; j < 4; ++j) {
                    int row = m0 + wm * 128 + mt * 16 + kg * 4 + j;
                    float v = acc[mt][nt][j] + bv;
                    if (RELU) v = fmaxf(v, 0.f);
                    ((unsigned short*)Cptr)[(long)g * sCg + (long)row * N + col] = f2bf(v);
                }
            }
        }
    }
}

// ---------- K3b: 128x128 tile GEMM (m97 structure) — used only for cq GEMM3 (N=128) ----------
template<int EPI, bool RELU>   // EPI: 0 bf16 store, 2 f32 store
__global__ __launch_bounds__(256, 2)
void gemm_kernel(const unsigned short* __restrict__ A,
                 const unsigned short* __restrict__ Bt,
                 const float* __restrict__ bias,
                 void* __restrict__ Cptr,
                 int nM, int nN, int K,
                 long sAg, long sBg, long sCg, int sBiasG, int biasN) {
    unsigned tot = gridDim.x;
    unsigned bid = blockIdx.x;
    unsigned sw = (tot & 7u) == 0 ? (bid & 7u) * (tot >> 3) + (bid >> 3) : bid;
    unsigned pg = (unsigned)nM * (unsigned)nN;
    unsigned g = sw / pg;
    unsigned rem = sw - g * pg;
    unsigned mt_ = rem / (unsigned)nN;
    unsigned nt_ = rem - mt_ * (unsigned)nN;
    const int N = nN * 128;
    A += (long)g * sAg;
    Bt += (long)g * sBg;
    bias += (long)g * sBiasG;
    const int m0 = (int)mt_ * 128;
    const int n0 = (int)nt_ * 128;

    __shared__ __align__(16) unsigned short ldsA[128 * 32];
    __shared__ __align__(16) unsigned short ldsB[128 * 32];

    const int tid = threadIdx.x;
    const int lane = tid & 63;
    const int w = tid >> 6;
    const int wm = w >> 1, wn = w & 1;
    const int r16 = lane & 15, kg = lane >> 4;

    f32x4 acc[4][4];
#pragma unroll
    for (int i = 0; i < 4; ++i)
#pragma unroll
        for (int j = 0; j < 4; ++j) {
            f32x4 z = {0.f, 0.f, 0.f, 0.f};
            acc[i][j] = z;
        }

    for (int k0 = 0; k0 < K; k0 += 32) {
#pragma unroll
        for (int j = 0; j < 2; ++j) {
            int t = j * 256 + tid;
            int row = t >> 2, kc = (t & 3) * 8;
            const unsigned short* ga = A + (long)(m0 + row) * K + k0 + kc;
            __builtin_amdgcn_global_load_lds(
                (const __attribute__((address_space(1))) void*)ga,
                (__attribute__((address_space(3))) void*)(ldsA + (j * 256 + w * 64) * 8),
                16, 0, 0);
            const unsigned short* gb = Bt + (long)(n0 + row) * K + k0 + kc;
            __builtin_amdgcn_global_load_lds(
                (const __attribute__((address_space(1))) void*)gb,
                (__attribute__((address_space(3))) void*)(ldsB + (j * 256 + w * 64) * 8),
                16, 0, 0);
        }
        __syncthreads();
        short8 aF[4], bF[4];
#pragma unroll
        for (int mt = 0; mt < 4; ++mt)
            aF[mt] = *(const short8*)(ldsA + (wm * 64 + mt * 16 + r16) * 32 + kg * 8);
#pragma unroll
        for (int nt = 0; nt < 4; ++nt)
            bF[nt] = *(const short8*)(ldsB + (wn * 64 + nt * 16 + r16) * 32 + kg * 8);
#pragma unroll
        for (int mt = 0; mt < 4; ++mt)
#pragma unroll
            for (int nt = 0; nt < 4; ++nt)
                acc[mt][nt] = __builtin_amdgcn_mfma_f32_16x16x32_bf16(
                    aF[mt], bF[nt], acc[mt][nt], 0, 0, 0);
        __syncthreads();
    }

#pragma unroll
    for (int nt = 0; nt < 4; ++nt) {
        int col = n0 + wn * 64 + nt * 16 + r16;
        float bv = (col < biasN) ? bias[col] : 0.f;
#pragma unroll
        for (int mt = 0; mt < 4; ++mt) {
#pragma unroll
            for (int j = 0; j < 4; ++j) {
                int row = m0 + wm * 64 + mt * 16 + kg * 4 + j;
                float v = acc[mt][nt][j] + bv;
                if (RELU) v = fmaxf(v, 0.f);
                if constexpr (EPI == 0)
                    ((unsigned short*)Cptr)[(long)g * sCg + (long)row * N + col] = f2bf(v);
                else
                    ((float*)Cptr)[(long)g * sCg + (long)row * N + col] = v;
            }
        }
    }
}

// ---------- K5: fire = softmax over rules ----------
__global__ __launch_bounds__(256)
void fire_kernel(const float* __restrict__ fslog, float* __restrict__ fire) {
    int b = blockIdx.x * 256 + threadIdx.x;
    float v[32];
    float mx = -1e30f;
#pragma unroll
    for (int r = 0; r < 32; ++r) { v[r] = fslog[r * 2048 + b]; mx = fmaxf(mx, v[r]); }
    float s = 0.f;
#pragma unroll
    for (int r = 0; r < 32; ++r) { v[r] = __expf(v[r] - mx); s += v[r]; }
    float inv = 1.f / s;
#pragma unroll
    for (int r = 0; r < 32; ++r) fire[b * 32 + r] = v[r] * inv;
}

// ---------- K6: mix accumulate ----------
__global__ __launch_bounds__(128)
void accum_kernel(const float* __restrict__ logits, const float* __restrict__ fire,
                  float* __restrict__ mix, int r0, int NR, int first) {
    int b = blockIdx.x, c = threadIdx.x;
    float acc = first ? 0.f : mix[b * 128 + c];
    for (int r = 0; r < NR; ++r)
        acc += fire[b * 32 + r0 + r] * logits[((long)r * 2048 + b) * 128 + c];
    mix[b * 128 + c] = acc;
}

// ---------- K7: class softmax ----------
__global__ __launch_bounds__(128)
void softmax_out_kernel(const float* __restrict__ mix, float* __restrict__ out) {
    int b = blockIdx.x, c = threadIdx.x;
    __shared__ float redm[2], reds[2];
    float val = (c < 100) ? mix[b * 128 + c] : -1e30f;
    float m = val;
#pragma unroll
    for (int off = 32; off; off >>= 1) m = fmaxf(m, __shfl_xor(m, off, 64));
    int lane = c & 63, wv = c >> 6;
    if (lane == 0) redm[wv] = m;
    __syncthreads();
    m = fmaxf(redm[0], redm[1]);
    float e = (c < 100) ? __expf(val - m) : 0.f;
    float s = e;
#pragma unroll
    for (int off = 32; off; off >>= 1) s += __shfl_xor(s, off, 64);
    if (lane == 0) reds[wv] = s;
    __syncthreads();
    s = reds[0] + reds[1];
    if (c < 100) out[b * 100 + c] = e / s;
}

// ---------- launch ----------
extern "C" void kernel_launch(void* const* d_in, const int* in_sizes, int n_in,
                              void* d_out, int out_size, void* d_ws, size_t ws_size,
                              hipStream_t stream) {
    const float* data  = (const float*)d_in[0];
    const float* proto = (const float*)d_in[1];
    const float* var   = (const float*)d_in[2];
    const float* fs_w1 = (const float*)d_in[3];
    const float* fs_b1 = (const float*)d_in[4];
    const float* fs_w2 = (const float*)d_in[5];
    const float* fs_b2 = (const float*)d_in[6];
    const float* fs_w3 = (const float*)d_in[7];
    const float* cq_w1 = (const float*)d_in[9];
    const float* cq_b1 = (const float*)d_in[10];
    const float* cq_w2 = (const float*)d_in[11];
    const float* cq_b2 = (const float*)d_in[12];
    const float* cq_w3 = (const float*)d_in[13];
    const float* cq_b3 = (const float*)d_in[14];
    float* out = (float*)d_out;

    // ---- adaptive workspace: p1r pass-1 rules/chunk, p2r pass-2 rules/chunk ----
    const size_t PERSIST = 2097152 + 1048576 + 1048576 + 262144 + 262144 + 1048576;
    const size_t PER_RULE_P2 = 1048576 + 1048576 + 131072 + 2097152;
    auto need = [&](int p1r, int p2r) -> size_t {
        size_t logitsC = (size_t)p2r * 2048 * 128 * 4;
        size_t R0 = (size_t)p1r * 2048 * 512 * 2;
        size_t r0p2 = (size_t)p2r * PER_RULE_P2;
        if (r0p2 > R0) R0 = r0p2;
        size_t R1 = (size_t)p1r * 2048 * 1024 * 2;
        size_t g1b = (size_t)p2r * 2048 * 1024 * 2;
        if (g1b > R1) R1 = g1b;
        return PERSIST + logitsC + R0 + R1;
    };
    int p1r = 32, p2r = 16;
    while (need(p1r, p2r) > ws_size && p1r > 2) { p1r >>= 1; p2r >>= 1; }

    char* ws = (char*)d_ws;
    size_t off = 0;
    auto take = [&](size_t bytes) { char* p = ws + off; off += bytes; return p; };
    unsigned short* data_bf = (unsigned short*)take(2097152);
    unsigned short* w1t     = (unsigned short*)take(1048576);
    unsigned short* w2t     = (unsigned short*)take(1048576);
    float*          fslog   = (float*)take(262144);
    float*          fire    = (float*)take(262144);
    float*          mix     = (float*)take(1048576);
    float*          logitsC = (float*)take((size_t)p2r * 2048 * 128 * 4);
    size_t R0sz = (size_t)p1r * 2048 * 512 * 2;
    { size_t t = (size_t)p2r * PER_RULE_P2; if (t > R0sz) R0sz = t; }
    char* R0 = take(R0sz);
    size_t R1sz = (size_t)p1r * 2048 * 1024 * 2;
    { size_t t = (size_t)p2r * 2048 * 1024 * 2; if (t > R1sz) R1sz = t; }
    char* R1 = take(R1sz);

    unsigned short* cF   = (unsigned short*)R0;
    unsigned short* cW1t = (unsigned short*)R0;
    unsigned short* cW2t = (unsigned short*)(R0 + (size_t)p2r * 1048576);
    unsigned short* cW3t = (unsigned short*)(R0 + (size_t)p2r * 2097152);
    unsigned short* g2   = (unsigned short*)(R0 + (size_t)p2r * 2097152 + (size_t)p2r * 131072);
    unsigned short* h1   = (unsigned short*)R1;
    unsigned short* g1   = (unsigned short*)R1;

    // ---- prologue ----
    cvt_bf16_kernel<<<1024, 256, 0, stream>>>(data, data_bf, 262144);
    transpose_kernel<<<dim3(16, 32, 1), 256, 0, stream>>>(fs_w1, w1t, 512, 1024, 1024);
    transpose_kernel<<<dim3(32, 16, 1), 256, 0, stream>>>(fs_w2, w2t, 1024, 512, 512);
    hipMemsetAsync(fslog, 0, 262144, stream);

    // ---- pass 1: fire-strength chain (fused GEMV epilogue) ----
    for (int ch = 0; ch < 32 / p1r; ++ch) {
        const int r0 = ch * p1r;
        fuzzy_kernel<<<p1r * 2048, 128, 0, stream>>>(data, proto, var, cF, r0);
        gemm256_kernel<0, true><<<p1r * 8 * 4, 512, 0, stream>>>(
            cF, w1t, fs_b1, h1, nullptr, nullptr,
            p1r * 8, 4, 512, 0, 0, 0, 0);
        gemm256_kernel<1, true><<<p1r * 8 * 2, 512, 0, stream>>>(
            h1, w2t, fs_b2, nullptr, fs_w3, fslog + (long)r0 * 2048,
            p1r * 8, 2, 1024, 0, 0, 0, 0);
    }
    fire_kernel<<<8, 256, 0, stream>>>(fslog, fire);

    // ---- pass 2: consequent chain, accumulate mixture ----
    for (int ch = 0; ch < 32 / p2r; ++ch) {
        const int r0 = ch * p2r;
        transpose_kernel<<<dim3(16, 32, p2r), 256, 0, stream>>>(
            cq_w1 + (long)r0 * 512 * 1024, cW1t, 512, 1024, 1024);
        transpose_kernel<<<dim3(32, 16, p2r), 256, 0, stream>>>(
            cq_w2 + (long)r0 * 1024 * 512, cW2t, 1024, 512, 512);
        transpose_kernel<<<dim3(16, 4, p2r), 256, 0, stream>>>(
            cq_w3 + (long)r0 * 512 * 100, cW3t, 512, 100, 128);
        gemm256_kernel<0, true><<<8 * 4 * p2r, 512, 0, stream>>>(
            data_bf, cW1t, cq_b1 + (long)r0 * 1024, g1, nullptr, nullptr,
            8, 4, 512, 0, (long)1024 * 512, (long)2048 * 1024, 1024);
        gemm256_kernel<0, true><<<8 * 2 * p2r, 512, 0, stream>>>(
            g1, cW2t, cq_b2 + (long)r0 * 512, g2, nullptr, nullptr,
            8, 2, 1024, (long)2048 * 1024, (long)512 * 1024, (long)2048 * 512, 512);
        gemm_kernel<2, false><<<16 * 1 * p2r, 256, 0, stream>>>(
            g2, cW3t, cq_b3 + (long)r0 * 100, logitsC,
            16, 1, 512, (long)2048 * 512, (long)128 * 512, (long)2048 * 128, 100, 100);
        accum_kernel<<<2048, 128, 0, stream>>>(logitsC, fire, mix, r0, p2r, ch == 0);
    }
    softmax_out_kernel<<<2048, 128, 0, stream>>>(mix, out);
}